// Round 8
// baseline (49.939 us; speedup 1.0000x reference)
//
#include <hip/hip_runtime.h>
#include <hip/hip_bf16.h>

// Problem constants: B=32768, D=768, C=200.
#define NROWS 32768
#define DIMS  768
#define NC    200
#define CPAD  256
#define KSTEP 32
#define NSTEP (DIMS / KSTEP)   // 24
#define ROWSB 32               // M-tile rows per block

typedef __attribute__((ext_vector_type(8))) short short8;   // 8 bf16
typedef __attribute__((ext_vector_type(4))) float f32x4;

__device__ __forceinline__ unsigned pk_bf16(float lo, float hi) {
  union { __hip_bfloat162 h; unsigned u; } c;
  c.h = __float22bfloat162_rn(make_float2(lo, hi));
  return c.u;
}

// Kernel 1: L2-normalize centers -> bf16, K-blocked layout:
// (c,d) -> cnb2[(d>>5)*CPAD*KSTEP + c*KSTEP + (d&31)]; rows >= NC zero.
// Also zeroes the output scalar.
__global__ __launch_bounds__(256) void prep_centers_k(const float* __restrict__ centers,
                                                      short* __restrict__ cnb2,
                                                      float* __restrict__ out) {
  const int c = blockIdx.x;
  const int tid = threadIdx.x;
  if (c == 0 && tid == 0) out[0] = 0.f;
  if (c >= NC) {
    for (int d = tid; d < DIMS; d += 256)
      cnb2[(d >> 5) * (CPAD * KSTEP) + c * KSTEP + (d & 31)] = 0;
    return;
  }
  float ssq = 0.f;
  for (int d = tid; d < DIMS; d += 256) {
    float v = centers[c * DIMS + d];
    ssq += v * v;
  }
#pragma unroll
  for (int off = 32; off > 0; off >>= 1) ssq += __shfl_down(ssq, off);
  __shared__ float red[4];
  const int wid = tid >> 6, lane = tid & 63;
  if (lane == 0) red[wid] = ssq;
  __syncthreads();
  const float tot = red[0] + red[1] + red[2] + red[3];
  const float inv = 1.f / fmaxf(sqrtf(tot), 1e-8f);
  for (int d = tid; d < DIMS; d += 256) {
    const float v = centers[c * DIMS + d] * inv;
    union { __hip_bfloat16 h; short s; } cv;
    cv.h = __float2bfloat16(v);
    cnb2[(d >> 5) * (CPAD * KSTEP) + c * KSTEP + (d & 31)] = cv.s;
  }
}

// Kernel 2: BARRIER-FREE K-loop.
//   - A tile (32 rows x 768 k, bf16) staged to LDS ONCE (one __syncthreads total).
//   - B fragments loaded straight from L2-resident cnb2 (coalesced 1 KB/instr),
//     depth-2 register prefetch in named slots -> no vmcnt(0) drains anywhere.
// LDS A layout: As[ks][row][32 shorts]; quad q stored at q ^ ((row>>1)&3).
// MFMA frag mapping (verified rounds 2-7): A lane=A[m][kg*8+j]; B lane=B[kg*8+j][m];
// D: col=m, row=kg*4+reg.
__global__ __launch_bounds__(256, 3) void cos_loss_k(
    const float* __restrict__ feats,
    const short* __restrict__ cnb2,
    const int* __restrict__ labels,
    const int* __restrict__ labelled,
    float* __restrict__ out) {
  const int tid = threadIdx.x;
  const int w = tid >> 6;            // wave id = column group (64 cols)
  const int lane = tid & 63;
  const int m = lane & 15;
  const int kg = lane >> 4;
  const int rowBase = blockIdx.x * ROWSB;

  __shared__ short As[NSTEP][ROWSB][32];   // 48 KB
  __shared__ float invs[ROWSB];
  __shared__ int   labLds[ROWSB];
  __shared__ int   lblLds[ROWSB];
  __shared__ float l1part[4][ROWSB];
  __shared__ float alpart[4][ROWSB];

  if (tid < ROWSB) {
    labLds[tid] = labels[rowBase + tid];
    lblLds[tid] = labelled[rowBase + tid];
  }

  // ---- Stage A once: 8 threads/row, each handles 12 quads (quad = 8 bf16) ----
  {
    const int r = tid >> 3;          // 0..31
    const int c = tid & 7;           // 0..7
    const float* src = feats + (size_t)(rowBase + r) * DIMS;
    float ssq = 0.f;
#pragma unroll 6
    for (int j = 0; j < 12; ++j) {
      const int q = c + j * 8;                   // quad index 0..95
      const float4 va = *(const float4*)(src + q * 8);
      const float4 vb = *(const float4*)(src + q * 8 + 4);
      ssq += va.x*va.x + va.y*va.y + va.z*va.z + va.w*va.w;
      ssq += vb.x*vb.x + vb.y*vb.y + vb.z*vb.z + vb.w*vb.w;
      union { short8 s; unsigned u[4]; } p;
      p.u[0] = pk_bf16(va.x, va.y); p.u[1] = pk_bf16(va.z, va.w);
      p.u[2] = pk_bf16(vb.x, vb.y); p.u[3] = pk_bf16(vb.z, vb.w);
      const int ks = q >> 2;
      const int kq = (q & 3) ^ ((r >> 1) & 3);   // quad swizzle
      *(short8*)(&As[ks][r][kq * 8]) = p.s;
    }
#pragma unroll
    for (int off = 1; off < 8; off <<= 1) ssq += __shfl_xor(ssq, off);
    if (c == 0) invs[r] = 1.f / fmaxf(sqrtf(ssq), 1e-8f);
  }
  __syncthreads();   // the ONLY barrier before the epilogue

  // ---- Barrier-free K-loop with depth-2 B prefetch ----
  f32x4 acc[2][4];
#pragma unroll
  for (int mi = 0; mi < 2; ++mi)
#pragma unroll
    for (int ni = 0; ni < 4; ++ni) acc[mi][ni] = (f32x4){0.f, 0.f, 0.f, 0.f};

  // B frag base: col = w*64 + m; per step +CPAD*KSTEP shorts; per ni +16*KSTEP.
  const short* bp = cnb2 + (size_t)(w * 64 + m) * KSTEP + kg * 8;
  const int sq = (kg ^ ((m >> 1) & 3)) * 8;     // A-frag swizzled quad offset

  short8 P0b0, P0b1, P0b2, P0b3;
  short8 P1b0, P1b1, P1b2, P1b3;

#define LOADB(P, step) do {                                              \
    const short* bs_ = bp + (size_t)(step) * (CPAD * KSTEP);             \
    P##0 = *(const short8*)(bs_ + 0 * (16 * KSTEP));                     \
    P##1 = *(const short8*)(bs_ + 1 * (16 * KSTEP));                     \
    P##2 = *(const short8*)(bs_ + 2 * (16 * KSTEP));                     \
    P##3 = *(const short8*)(bs_ + 3 * (16 * KSTEP));                     \
  } while (0)

#define COMPUTE(P, ks) do {                                              \
    const short8 af0 = *(const short8*)(&As[(ks)][m][sq]);               \
    const short8 af1 = *(const short8*)(&As[(ks)][16 + m][sq]);          \
    acc[0][0] = __builtin_amdgcn_mfma_f32_16x16x32_bf16(af0, P##0, acc[0][0], 0, 0, 0); \
    acc[1][0] = __builtin_amdgcn_mfma_f32_16x16x32_bf16(af1, P##0, acc[1][0], 0, 0, 0); \
    acc[0][1] = __builtin_amdgcn_mfma_f32_16x16x32_bf16(af0, P##1, acc[0][1], 0, 0, 0); \
    acc[1][1] = __builtin_amdgcn_mfma_f32_16x16x32_bf16(af1, P##1, acc[1][1], 0, 0, 0); \
    acc[0][2] = __builtin_amdgcn_mfma_f32_16x16x32_bf16(af0, P##2, acc[0][2], 0, 0, 0); \
    acc[1][2] = __builtin_amdgcn_mfma_f32_16x16x32_bf16(af1, P##2, acc[1][2], 0, 0, 0); \
    acc[0][3] = __builtin_amdgcn_mfma_f32_16x16x32_bf16(af0, P##3, acc[0][3], 0, 0, 0); \
    acc[1][3] = __builtin_amdgcn_mfma_f32_16x16x32_bf16(af1, P##3, acc[1][3], 0, 0, 0); \
  } while (0)

  LOADB(P0b, 0);
  LOADB(P1b, 1);
  for (int ks = 0; ks < NSTEP; ks += 2) {
    COMPUTE(P0b, ks);
    if (ks + 2 < NSTEP) LOADB(P0b, ks + 2);
    COMPUTE(P1b, ks + 1);
    if (ks + 3 < NSTEP) LOADB(P1b, ks + 3);
  }

#undef LOADB
#undef COMPUTE

  // ---- Epilogue: per-row l1 and label-|cos| ----
#pragma unroll
  for (int mi = 0; mi < 2; ++mi) {
    float l1r[4] = {0.f, 0.f, 0.f, 0.f};
    float alr[4] = {0.f, 0.f, 0.f, 0.f};
    float iv[4];
    int labr[4];
#pragma unroll
    for (int r = 0; r < 4; ++r) {
      const int row = mi * 16 + kg * 4 + r;
      iv[r] = invs[row];
      labr[r] = labLds[row];
    }
#pragma unroll
    for (int ni = 0; ni < 4; ++ni) {
      const int col = w * 64 + ni * 16 + m;
#pragma unroll
      for (int r = 0; r < 4; ++r) {
        const float a = fabsf(acc[mi][ni][r] * iv[r]);
        l1r[r] += a;
        if (col == labr[r]) alr[r] += a;
      }
    }
#pragma unroll
    for (int r = 0; r < 4; ++r) {
#pragma unroll
      for (int off = 1; off < 16; off <<= 1) {
        l1r[r] += __shfl_xor(l1r[r], off);
        alr[r] += __shfl_xor(alr[r], off);
      }
    }
    if (m == 0) {
#pragma unroll
      for (int r = 0; r < 4; ++r) {
        l1part[w][mi * 16 + kg * 4 + r] = l1r[r];
        alpart[w][mi * 16 + kg * 4 + r] = alr[r];
      }
    }
  }
  __syncthreads();

  if (tid < ROWSB) {
    const float L = l1part[0][tid] + l1part[1][tid] + l1part[2][tid] + l1part[3][tid];
    const float A = alpart[0][tid] + alpart[1][tid] + alpart[2][tid] + alpart[3][tid];
    float c = lblLds[tid] ? (L - 2.f * A) / fmaxf(L, 1e-12f) : 0.f;
#pragma unroll
    for (int off = 1; off < 32; off <<= 1) c += __shfl_xor(c, off);
    if (tid == 0) atomicAdd(out, c);
  }
}

extern "C" void kernel_launch(void* const* d_in, const int* in_sizes, int n_in,
                              void* d_out, int out_size, void* d_ws, size_t ws_size,
                              hipStream_t stream) {
  const float* feats = (const float*)d_in[0];
  const float* centers = (const float*)d_in[1];
  const int* labels = (const int*)d_in[2];
  const int* labelled = (const int*)d_in[3];
  float* out = (float*)d_out;
  short* cnb2 = (short*)d_ws;  // [24][256][32] bf16 = 393216 B

  prep_centers_k<<<CPAD, 256, 0, stream>>>(centers, cnb2, out);
  cos_loss_k<<<NROWS / ROWSB, 256, 0, stream>>>(feats, cnb2, labels, labelled, out);
}